// Round 4
// baseline (378.994 us; speedup 1.0000x reference)
//
#include <hip/hip_runtime.h>

// GNNModel fused via MFMA. R16 = R15 + (a) Am aliased into hf (phase-disjoint
// lifetimes: Am dead once bA frags are hoisted to VGPRs right after the
// adjacency barrier) -> LDS 37.5KB -> 24.6KB -> 5-6 blocks/CU residency cap
// (was 4); bA for BOTH halves persistent in regs (14 x half4v = 28 VGPR,
// launch_bounds (256,5) targets the <=96 VGPR / 5 waves-per-SIMD cliff);
// (b) MFMA C-init = bias at every site (proj / mix / layer-2 / out1) deleting
// ~220 v_add per wave (fp32 re-association only). Two extra start barriers
// (Am->bA WAR). Fragment-layout hf, conflict-free t-phase b128 reads.
// Adjacency bit-exact fp32; A = mask + eye (diag 2).

typedef _Float16 half4v __attribute__((ext_vector_type(4)));
typedef _Float16 half8v __attribute__((ext_vector_type(8)));
typedef float    float4v __attribute__((ext_vector_type(4)));

constexpr int PP = 12, DIN = 32, H = 128, HO = 64, DOUT = 3, NL = 3;
constexpr int NB = 8;                   // 8 batches = two 48-row halves
constexpr int AP2 = 72;                 // Am row stride (halves): 2-way banks only
constexpr int GTS = 136;                // gTT stride (halves)

// ws layout in halves: WinT[128][32] @0 ; WgT[3][128][128] @4096 ; W1T[64][128] @53248
constexpr int WS_WG = 4096, WS_W1 = 53248, WS_TOT = 61440;

__global__ __launch_bounds__(256)
void prep_weights(const float* __restrict__ W_in, const float* __restrict__ W_gcn,
                  const float* __restrict__ W_out1, _Float16* __restrict__ ws)
{
    int e = blockIdx.x * 256 + threadIdx.x;
    if (e < WS_WG) {                        // WinT[n][k] = W_in[k][n]
        int n = e >> 5, k = e & 31;
        ws[e] = (_Float16)W_in[k * H + n];
    } else if (e < WS_W1) {                 // WgT[l][n][k] = W_gcn[l][k][n]
        int e2 = e - WS_WG;
        int l = e2 >> 14, r = e2 & 16383, n = r >> 7, k = r & 127;
        ws[e] = (_Float16)W_gcn[l * (H * H) + k * H + n];
    } else if (e < WS_TOT) {                // W1T[o][k] = W_out1[k][o]
        int e3 = e - WS_W1;
        int o = e3 >> 7, k = e3 & 127;
        ws[e] = (_Float16)W_out1[k * HO + o];
    }
}

__device__ inline half4v pk4(float a, float b, float c, float d) {
    half4v r; r[0] = (_Float16)a; r[1] = (_Float16)b; r[2] = (_Float16)c; r[3] = (_Float16)d;
    return r;
}

__global__ __launch_bounds__(256, 5)
void gnn_mfma(const float* __restrict__ x,
              const float* __restrict__ b_in,
              const float* __restrict__ b_gcn,
              const float* __restrict__ b_out1,
              const float* __restrict__ W_out2,
              const float* __restrict__ b_out2,
              const _Float16* __restrict__ ws,
              float* __restrict__ out)
{
    // Per half h: hf[h][mt*4+kt][lane*8+j] = h[16*mt+(lane&15)][32*kt+8*(lane>>4)+j]
    // ONLY LDS allocation (24 KB). Am / gTT / psf alias it with disjoint lifetimes:
    //   Am  [0, 13824) halves : adjacency write -> bA reg hoist   (phase 0)
    //   hf  full              : proj write -> layer-2 t-phase read (phase 1)
    //   gTT [hf[0]] / psf [hf[1]] : layer-2 pool -> tail           (phase 2)
    __shared__ __align__(16) _Float16 hf[2][12][512];   // 24 KB
    _Float16* Am  = &hf[0][0][0];
    _Float16* gTT = &hf[0][0][0];
    float*    psf = (float*)&hf[1][0][0];

    const int tid  = threadIdx.x;
    const int lane = tid & 63, wave = tid >> 6;
    const int q = lane >> 4, qm = lane & 15;
    const int hh = lane >> 5, l32 = lane & 31;          // adjacency half / lane-in-half
    const int b0 = blockIdx.x * NB;
    const float* xblk = x + (size_t)b0 * (PP * DIN);
    const _Float16* WgT = ws + WS_WG;

    // ---- lon + half-A x loads (issued early) ----
    float lon_own = 0.f;
    if (l32 < PP) lon_own = xblk[(hh * 48 + wave * PP + l32) * DIN];
    float4 xa[3], xb[3];
    #pragma unroll
    for (int nt = 0; nt < 3; ++nt) {
        const float* p = xblk + (16 * nt + qm) * DIN + 8 * q;
        xa[nt] = *(const float4*)p;
        xb[nt] = *(const float4*)(p + 4);
    }

    // ---- adjacency, BOTH halves in one pass (width-32 shuffles) ----
    {
        float lonj[PP];
        #pragma unroll
        for (int j = 0; j < PP; ++j) lonj[j] = __shfl(lon_own, j, 32);
        float deg = 1.0f;                              // GCNConv's appended self-loop
        #pragma unroll
        for (int j = 0; j < PP; ++j) {
            float d = fabsf(lon_own - lonj[j]);
            d = fminf(d, 360.0f - d);
            deg += (d < 10.0f) ? 1.0f : 0.0f;          // diag: d=0 -> 1
        }
        float dinv_own = rsqrtf(fmaxf(deg, 1e-12f));
        float dj[PP];
        #pragma unroll
        for (int j = 0; j < PP; ++j) dj[j] = __shfl(dinv_own, j, 32);

        if (l32 < PP) {
            _Float16* Ar = Am + (hh * 48 + wave * PP + l32) * AP2;
            half8v z = {0, 0, 0, 0, 0, 0, 0, 0};
            #pragma unroll
            for (int c = 0; c < 48; c += 8) *(half8v*)&Ar[c] = z;
            _Float16 vals[PP];
            #pragma unroll
            for (int j = 0; j < PP; ++j) {
                float d = fabsf(lon_own - lonj[j]);
                d = fminf(d, 360.0f - d);
                float a = (d < 10.0f) ? 1.0f : 0.0f;
                if (j == l32) a += 1.0f;               // A = mask + eye: diag = 2
                vals[j] = (_Float16)(a * dinv_own * dj[j]);
            }
            #pragma unroll
            for (int t4 = 0; t4 < 3; ++t4) {
                half4v v;
                v[0] = vals[4 * t4]; v[1] = vals[4 * t4 + 1];
                v[2] = vals[4 * t4 + 2]; v[3] = vals[4 * t4 + 3];
                *(half4v*)&Ar[wave * PP + 4 * t4] = v;
            }
        }
    }
    __syncthreads();   // A1: Am complete (all waves)

    // ---- hoist Ahat frags to VGPRs, BOTH halves (14 x half4v = 28 VGPR).
    // bAf[h] tiles (mt,nt): [0]=(0,0) [1]=(1,0) [2]=(0,1) [3]=(1,1) [4]=(2,1)
    // [5]=(1,2) [6]=(2,2); zero tiles (2,0),(0,2) skipped.
    // As B-frag: B[k=4q+j][col=qm] = Ahat[16nt+col][16mt+k]   (layers 0,1 mix)
    // As A-frag: A[row=qm][k=4q+j] = Ahat[16nt+row][16mt+k]   (layer 2 mix')
    half4v bAf[2][7];
    #pragma unroll
    for (int h = 0; h < 2; ++h) {
        const _Float16* Ah = Am + h * 48 * AP2;
        bAf[h][0] = *(const half4v*)&Ah[qm * AP2 + 4 * q];
        bAf[h][1] = *(const half4v*)&Ah[qm * AP2 + 16 + 4 * q];
        bAf[h][2] = *(const half4v*)&Ah[(16 + qm) * AP2 + 4 * q];
        bAf[h][3] = *(const half4v*)&Ah[(16 + qm) * AP2 + 16 + 4 * q];
        bAf[h][4] = *(const half4v*)&Ah[(16 + qm) * AP2 + 32 + 4 * q];
        bAf[h][5] = *(const half4v*)&Ah[(32 + qm) * AP2 + 16 + 4 * q];
        bAf[h][6] = *(const half4v*)&Ah[(32 + qm) * AP2 + 32 + 4 * q];
    }
    __syncthreads();   // A2: WAR — all bA reads done before proj overwrites hf

    // ---- pack half-A x, then issue half-B x loads (latency under proj-A) ----
    half8v bxA[3];
    #pragma unroll
    for (int nt = 0; nt < 3; ++nt) {
        half8v h;
        h[0] = (_Float16)xa[nt].x; h[1] = (_Float16)xa[nt].y;
        h[2] = (_Float16)xa[nt].z; h[3] = (_Float16)xa[nt].w;
        h[4] = (_Float16)xb[nt].x; h[5] = (_Float16)xb[nt].y;
        h[6] = (_Float16)xb[nt].z; h[7] = (_Float16)xb[nt].w;
        bxA[nt] = h;
    }
    #pragma unroll
    for (int nt = 0; nt < 3; ++nt) {
        const float* p = xblk + (48 + 16 * nt + qm) * DIN + 8 * q;
        xa[nt] = *(const float4*)p;
        xb[nt] = *(const float4*)(p + 4);
    }

    // ---- proj: both halves share the SAME aw/bias registers; C-init = bias ----
    {
        const int m0 = 32 * wave, m1 = 32 * wave + 16;
        half8v aw0 = *(const half8v*)&ws[(m0 + qm) * DIN + 8 * q];
        half8v aw1 = *(const half8v*)&ws[(m1 + qm) * DIN + 8 * q];
        float4 bi0 = *(const float4*)&b_in[m0 + 4 * q];
        float4 bi1 = *(const float4*)&b_in[m1 + 4 * q];
        const float4v ci0 = {bi0.x, bi0.y, bi0.z, bi0.w};   // C rows = ch 4q+r
        const float4v ci1 = {bi1.x, bi1.y, bi1.z, bi1.w};
        const int ho0 = (qm + 16 * ((q >> 1) & 3)) * 8 + (q & 1) * 4;        // mt2=0
        const int ho1 = (qm + 16 * ((2 + (q >> 1)) & 3)) * 8 + (q & 1) * 4;  // mt2=1
        #pragma unroll
        for (int nt = 0; nt < 3; ++nt) {
            float4v c0 = ci0, c1 = ci1;
            c0 = __builtin_amdgcn_mfma_f32_16x16x32_f16(aw0, bxA[nt], c0, 0, 0, 0);
            c1 = __builtin_amdgcn_mfma_f32_16x16x32_f16(aw1, bxA[nt], c1, 0, 0, 0);
            *(half4v*)&hf[0][nt * 4 + wave][ho0] = pk4(c0[0], c0[1], c0[2], c0[3]);
            *(half4v*)&hf[0][nt * 4 + wave][ho1] = pk4(c1[0], c1[1], c1[2], c1[3]);
        }
        half8v bxB[3];
        #pragma unroll
        for (int nt = 0; nt < 3; ++nt) {
            half8v h;
            h[0] = (_Float16)xa[nt].x; h[1] = (_Float16)xa[nt].y;
            h[2] = (_Float16)xa[nt].z; h[3] = (_Float16)xa[nt].w;
            h[4] = (_Float16)xb[nt].x; h[5] = (_Float16)xb[nt].y;
            h[6] = (_Float16)xb[nt].z; h[7] = (_Float16)xb[nt].w;
            bxB[nt] = h;
        }
        #pragma unroll
        for (int nt = 0; nt < 3; ++nt) {
            float4v c0 = ci0, c1 = ci1;
            c0 = __builtin_amdgcn_mfma_f32_16x16x32_f16(aw0, bxB[nt], c0, 0, 0, 0);
            c1 = __builtin_amdgcn_mfma_f32_16x16x32_f16(aw1, bxB[nt], c1, 0, 0, 0);
            *(half4v*)&hf[1][nt * 4 + wave][ho0] = pk4(c0[0], c0[1], c0[2], c0[3]);
            *(half4v*)&hf[1][nt * 4 + wave][ho1] = pk4(c1[0], c1[1], c1[2], c1[3]);
        }
    }

    // ---- layer-0 weight B-frags: issue BEFORE the barrier (latency hidden) ----
    half8v bw[2][4];
    #pragma unroll
    for (int n2 = 0; n2 < 2; ++n2)
        #pragma unroll
        for (int kt = 0; kt < 4; ++kt)
            bw[n2][kt] = *(const half8v*)&WgT[(32 * wave + 16 * n2 + qm) * H + 32 * kt + 8 * q];

    __syncthreads();   // B1: hf (both halves) complete

    #pragma unroll
    for (int l = 0; l < NL; ++l) {
        // t = h @ Wl for both halves, SHARED bw registers (all-static indexing)
        half4v ah[2][3][2];
        #pragma unroll
        for (int h = 0; h < 2; ++h) {
            float4v c[3][2];
            #pragma unroll
            for (int mt = 0; mt < 3; ++mt) {
                c[mt][0] = (float4v){0.f, 0.f, 0.f, 0.f};
                c[mt][1] = (float4v){0.f, 0.f, 0.f, 0.f};
            }
            #pragma unroll
            for (int kt = 0; kt < 4; ++kt)
                #pragma unroll
                for (int mt = 0; mt < 3; ++mt) {
                    half8v a = *(const half8v*)&hf[h][mt * 4 + kt][lane * 8];
                    c[mt][0] = __builtin_amdgcn_mfma_f32_16x16x32_f16(a, bw[0][kt], c[mt][0], 0, 0, 0);
                    c[mt][1] = __builtin_amdgcn_mfma_f32_16x16x32_f16(a, bw[1][kt], c[mt][1], 0, 0, 0);
                }
            #pragma unroll
            for (int mt = 0; mt < 3; ++mt)
                #pragma unroll
                for (int n2 = 0; n2 < 2; ++n2)
                    ah[h][mt][n2] = pk4(c[mt][n2][0], c[mt][n2][1], c[mt][n2][2], c[mt][n2][3]);
        }

        if (l < 2) {
            const float4 bg0 = *(const float4*)&b_gcn[l * H + 32 * wave + 4 * q];
            const float4 bg1 = *(const float4*)&b_gcn[l * H + 32 * wave + 16 + 4 * q];
            __syncthreads();   // WAR: all waves done reading hf (both halves)

            // prefetch next layer's W frags (bw dead; drains at RAW barrier)
            {
                const _Float16* Wn = WgT + (l + 1) * (H * H);
                #pragma unroll
                for (int n2 = 0; n2 < 2; ++n2)
                    #pragma unroll
                    for (int kt = 0; kt < 4; ++kt)
                        bw[n2][kt] = *(const half8v*)&Wn[(32 * wave + 16 * n2 + qm) * H + 32 * kt + 8 * q];
            }

            // mix per half: h'^T = t^T @ Ahat_h (bA persistent regs; D-init = bias)
            #pragma unroll
            for (int h = 0; h < 2; ++h) {
                #pragma unroll
                for (int n2 = 0; n2 < 2; ++n2) {
                    const float4 bg = n2 ? bg1 : bg0;
                    const float4v di = {bg.x, bg.y, bg.z, bg.w};   // D rows = ch 4q+r
                    const int hoff = (qm + 16 * ((2 * n2 + (q >> 1)) & 3)) * 8 + (q & 1) * 4;

                    float4v d0 = di;
                    d0 = __builtin_amdgcn_mfma_f32_16x16x16f16(ah[h][0][n2], bAf[h][0], d0, 0, 0, 0);
                    d0 = __builtin_amdgcn_mfma_f32_16x16x16f16(ah[h][1][n2], bAf[h][1], d0, 0, 0, 0);
                    *(half4v*)&hf[h][0 * 4 + wave][hoff] =
                        pk4(fmaxf(d0[0], 0.f), fmaxf(d0[1], 0.f),
                            fmaxf(d0[2], 0.f), fmaxf(d0[3], 0.f));

                    float4v d1 = di;
                    d1 = __builtin_amdgcn_mfma_f32_16x16x16f16(ah[h][0][n2], bAf[h][2], d1, 0, 0, 0);
                    d1 = __builtin_amdgcn_mfma_f32_16x16x16f16(ah[h][1][n2], bAf[h][3], d1, 0, 0, 0);
                    d1 = __builtin_amdgcn_mfma_f32_16x16x16f16(ah[h][2][n2], bAf[h][4], d1, 0, 0, 0);
                    *(half4v*)&hf[h][1 * 4 + wave][hoff] =
                        pk4(fmaxf(d1[0], 0.f), fmaxf(d1[1], 0.f),
                            fmaxf(d1[2], 0.f), fmaxf(d1[3], 0.f));

                    float4v d2 = di;
                    d2 = __builtin_amdgcn_mfma_f32_16x16x16f16(ah[h][1][n2], bAf[h][5], d2, 0, 0, 0);
                    d2 = __builtin_amdgcn_mfma_f32_16x16x16f16(ah[h][2][n2], bAf[h][6], d2, 0, 0, 0);
                    *(half4v*)&hf[h][2 * 4 + wave][hoff] =
                        pk4(fmaxf(d2[0], 0.f), fmaxf(d2[1], 0.f),
                            fmaxf(d2[2], 0.f), fmaxf(d2[3], 0.f));
                }
            }
            __syncthreads();   // RAW for next layer
        } else {
            // ---- layer 2: mix' = Ahat @ t per half (bA as A-frags, D-init = bias);
            // pool in-lane + shfl_xor; gTT aliases dead hf[0].
            __syncthreads();   // all hf reads done -> gTT/psf alias of hf is safe
            const float bgc0 = b_gcn[2 * H + 32 * wave + qm];
            const float bgc1 = b_gcn[2 * H + 32 * wave + 16 + qm];
            #pragma unroll
            for (int h = 0; h < 2; ++h) {
                float s[3][2];
                #pragma unroll
                for (int n2 = 0; n2 < 2; ++n2) {
                    const float bgc = n2 ? bgc1 : bgc0;
                    const float4v di = {bgc, bgc, bgc, bgc};   // D cols = ch qm (lane-uniform)
                    float4v d;
                    d = di;
                    d = __builtin_amdgcn_mfma_f32_16x16x16f16(bAf[h][0], ah[h][0][n2], d, 0, 0, 0);
                    d = __builtin_amdgcn_mfma_f32_16x16x16f16(bAf[h][1], ah[h][1][n2], d, 0, 0, 0);
                    s[0][n2] = fmaxf(d[0], 0.f) + fmaxf(d[1], 0.f)
                             + fmaxf(d[2], 0.f) + fmaxf(d[3], 0.f);
                    d = di;
                    d = __builtin_amdgcn_mfma_f32_16x16x16f16(bAf[h][2], ah[h][0][n2], d, 0, 0, 0);
                    d = __builtin_amdgcn_mfma_f32_16x16x16f16(bAf[h][3], ah[h][1][n2], d, 0, 0, 0);
                    d = __builtin_amdgcn_mfma_f32_16x16x16f16(bAf[h][4], ah[h][2][n2], d, 0, 0, 0);
                    s[1][n2] = fmaxf(d[0], 0.f) + fmaxf(d[1], 0.f)
                             + fmaxf(d[2], 0.f) + fmaxf(d[3], 0.f);
                    d = di;
                    d = __builtin_amdgcn_mfma_f32_16x16x16f16(bAf[h][5], ah[h][1][n2], d, 0, 0, 0);
                    d = __builtin_amdgcn_mfma_f32_16x16x16f16(bAf[h][6], ah[h][2][n2], d, 0, 0, 0);
                    s[2][n2] = fmaxf(d[0], 0.f) + fmaxf(d[1], 0.f)
                             + fmaxf(d[2], 0.f) + fmaxf(d[3], 0.f);
                }
                // batch(rt,q): b0:(0,q<=2) b1:(0,3)(1,0)(1,1) b2:(1,2)(1,3)(2,0) b3:(2,q>=1)
                #pragma unroll
                for (int n2 = 0; n2 < 2; ++n2) {
                    float g4[4];
                    g4[0] = (q <= 2) ? s[0][n2] : 0.f;
                    g4[1] = (q == 3) ? s[0][n2] : ((q <= 1) ? s[1][n2] : 0.f);
                    g4[2] = (q >= 2) ? s[1][n2] : ((q == 0) ? s[2][n2] : 0.f);
                    g4[3] = (q >= 1) ? s[2][n2] : 0.f;
                    #pragma unroll
                    for (int b = 0; b < 4; ++b) {
                        float v = g4[b];
                        v += __shfl_xor(v, 16, 64);
                        v += __shfl_xor(v, 32, 64);
                        if (q == 0)
                            gTT[(4 * h + b) * GTS + 32 * wave + 16 * n2 + qm] =
                                (_Float16)(v * (1.0f / 12.0f));
                    }
                }
            }
            __syncthreads();   // gTT complete
        }
    }

    // ---- out1 via MFMA: o1^T = W1T @ g^T; C-init = b_out1 ----
    const float4 b1v = *(const float4*)&b_out1[16 * wave + 4 * q];
    float4v acc = {b1v.x, b1v.y, b1v.z, b1v.w};
    #pragma unroll
    for (int kt = 0; kt < 4; ++kt) {
        half8v aW = *(const half8v*)&ws[WS_W1 + (16 * wave + qm) * H + 32 * kt + 8 * q];
        half8v bG = *(const half8v*)&gTT[qm * GTS + 32 * kt + 8 * q];
        acc = __builtin_amdgcn_mfma_f32_16x16x32_f16(aW, bG, acc, 0, 0, 0);
    }
    // lane holds o1T[o=16w+4q+r][b=qm] (valid qm<8; qm>=8 garbage, discarded)
    float o1v[4];
    o1v[0] = fmaxf(acc[0], 0.f);
    o1v[1] = fmaxf(acc[1], 0.f);
    o1v[2] = fmaxf(acc[2], 0.f);
    o1v[3] = fmaxf(acc[3], 0.f);
    const float* w2p = W_out2 + (16 * wave + 4 * q) * DOUT;   // 16B-aligned
    const float4 w2a = *(const float4*)(w2p);
    const float4 w2b = *(const float4*)(w2p + 4);
    const float4 w2c = *(const float4*)(w2p + 8);
    float p0 = o1v[0] * w2a.x + o1v[1] * w2a.w + o1v[2] * w2b.z + o1v[3] * w2c.y;
    float p1 = o1v[0] * w2a.y + o1v[1] * w2b.x + o1v[2] * w2b.w + o1v[3] * w2c.z;
    float p2 = o1v[0] * w2a.z + o1v[1] * w2b.y + o1v[2] * w2c.x + o1v[3] * w2c.w;
    p0 += __shfl_xor(p0, 16, 64); p0 += __shfl_xor(p0, 32, 64);
    p1 += __shfl_xor(p1, 16, 64); p1 += __shfl_xor(p1, 32, 64);
    p2 += __shfl_xor(p2, 16, 64); p2 += __shfl_xor(p2, 32, 64);
    if (q == 0 && qm < NB) {
        psf[wave * (NB * DOUT) + qm * DOUT + 0] = p0;
        psf[wave * (NB * DOUT) + qm * DOUT + 1] = p1;
        psf[wave * (NB * DOUT) + qm * DOUT + 2] = p2;
    }
    __syncthreads();
    if (tid < NB * DOUT) {   // 24
        const int b = tid / 3, d = tid - 3 * b;
        const float ssum = psf[b * 3 + d] + psf[24 + b * 3 + d]
                         + psf[48 + b * 3 + d] + psf[72 + b * 3 + d] + b_out2[d];
        out[(size_t)(b0 + b) * DOUT + d] = ssum;
    }
}

extern "C" void kernel_launch(void* const* d_in, const int* in_sizes, int n_in,
                              void* d_out, int out_size, void* d_ws, size_t ws_size,
                              hipStream_t stream) {
    const float* x      = (const float*)d_in[0];
    const float* W_in   = (const float*)d_in[1];
    const float* b_in   = (const float*)d_in[2];
    const float* W_gcn  = (const float*)d_in[3];
    const float* b_gcn  = (const float*)d_in[4];
    const float* W_out1 = (const float*)d_in[5];
    const float* b_out1 = (const float*)d_in[6];
    const float* W_out2 = (const float*)d_in[7];
    const float* b_out2 = (const float*)d_in[8];
    float* outp         = (float*)d_out;
    _Float16* wsh       = (_Float16*)d_ws;

    const int B = in_sizes[0] / (PP * DIN);        // 65536

    hipLaunchKernelGGL(prep_weights, dim3((WS_TOT + 255) / 256), dim3(256), 0, stream,
                       W_in, W_gcn, W_out1, wsh);
    hipLaunchKernelGGL(gnn_mfma, dim3(B / NB), dim3(256), 0, stream,
                       x, b_in, b_gcn, b_out1, W_out2, b_out2, wsh, outp);
}

// Round 5
// 296.819 us; speedup vs baseline: 1.2769x; 1.2769x over previous
//
#include <hip/hip_runtime.h>

// GNNModel fused via MFMA. R17 = R16 with __launch_bounds__(256,4): R16's
// (256,5) capped VGPR at ~96 < ~110 live set -> spilled ~34 dwords/thread to
// scratch (WRITE_SIZE 1MB->287MB, kernel became spill-BW-bound). Structure
// kept: Am aliased into hf (phase-disjoint; LDS 24.6KB), bA frags for BOTH
// halves persistent in VGPRs (28), MFMA C-init = bias everywhere, shared
// aw/bw/barriers across the two 48-row halves. Fragment-layout hf
// (conflict-free t-phase b128 reads). Adjacency bit-exact fp32.

typedef _Float16 half4v __attribute__((ext_vector_type(4)));
typedef _Float16 half8v __attribute__((ext_vector_type(8)));
typedef float    float4v __attribute__((ext_vector_type(4)));

constexpr int PP = 12, DIN = 32, H = 128, HO = 64, DOUT = 3, NL = 3;
constexpr int NB = 8;                   // 8 batches = two 48-row halves
constexpr int AP2 = 72;                 // Am row stride (halves): 2-way banks only
constexpr int GTS = 136;                // gTT stride (halves)

// ws layout in halves: WinT[128][32] @0 ; WgT[3][128][128] @4096 ; W1T[64][128] @53248
constexpr int WS_WG = 4096, WS_W1 = 53248, WS_TOT = 61440;

__global__ __launch_bounds__(256)
void prep_weights(const float* __restrict__ W_in, const float* __restrict__ W_gcn,
                  const float* __restrict__ W_out1, _Float16* __restrict__ ws)
{
    int e = blockIdx.x * 256 + threadIdx.x;
    if (e < WS_WG) {                        // WinT[n][k] = W_in[k][n]
        int n = e >> 5, k = e & 31;
        ws[e] = (_Float16)W_in[k * H + n];
    } else if (e < WS_W1) {                 // WgT[l][n][k] = W_gcn[l][k][n]
        int e2 = e - WS_WG;
        int l = e2 >> 14, r = e2 & 16383, n = r >> 7, k = r & 127;
        ws[e] = (_Float16)W_gcn[l * (H * H) + k * H + n];
    } else if (e < WS_TOT) {                // W1T[o][k] = W_out1[k][o]
        int e3 = e - WS_W1;
        int o = e3 >> 7, k = e3 & 127;
        ws[e] = (_Float16)W_out1[k * HO + o];
    }
}

__device__ inline half4v pk4(float a, float b, float c, float d) {
    half4v r; r[0] = (_Float16)a; r[1] = (_Float16)b; r[2] = (_Float16)c; r[3] = (_Float16)d;
    return r;
}

__global__ __launch_bounds__(256, 4)
void gnn_mfma(const float* __restrict__ x,
              const float* __restrict__ b_in,
              const float* __restrict__ b_gcn,
              const float* __restrict__ b_out1,
              const float* __restrict__ W_out2,
              const float* __restrict__ b_out2,
              const _Float16* __restrict__ ws,
              float* __restrict__ out)
{
    // Per half h: hf[h][mt*4+kt][lane*8+j] = h[16*mt+(lane&15)][32*kt+8*(lane>>4)+j]
    // ONLY LDS allocation (24 KB). Am / gTT / psf alias it with disjoint lifetimes:
    //   Am  [0, 13824) halves : adjacency write -> bA reg hoist   (phase 0)
    //   hf  full              : proj write -> layer-2 t-phase read (phase 1)
    //   gTT [hf[0]] / psf [hf[1]] : layer-2 pool -> tail           (phase 2)
    __shared__ __align__(16) _Float16 hf[2][12][512];   // 24 KB
    _Float16* Am  = &hf[0][0][0];
    _Float16* gTT = &hf[0][0][0];
    float*    psf = (float*)&hf[1][0][0];

    const int tid  = threadIdx.x;
    const int lane = tid & 63, wave = tid >> 6;
    const int q = lane >> 4, qm = lane & 15;
    const int hh = lane >> 5, l32 = lane & 31;          // adjacency half / lane-in-half
    const int b0 = blockIdx.x * NB;
    const float* xblk = x + (size_t)b0 * (PP * DIN);
    const _Float16* WgT = ws + WS_WG;

    // ---- lon + half-A x loads (issued early) ----
    float lon_own = 0.f;
    if (l32 < PP) lon_own = xblk[(hh * 48 + wave * PP + l32) * DIN];
    float4 xa[3], xb[3];
    #pragma unroll
    for (int nt = 0; nt < 3; ++nt) {
        const float* p = xblk + (16 * nt + qm) * DIN + 8 * q;
        xa[nt] = *(const float4*)p;
        xb[nt] = *(const float4*)(p + 4);
    }

    // ---- adjacency, BOTH halves in one pass (width-32 shuffles) ----
    {
        float lonj[PP];
        #pragma unroll
        for (int j = 0; j < PP; ++j) lonj[j] = __shfl(lon_own, j, 32);
        float deg = 1.0f;                              // GCNConv's appended self-loop
        #pragma unroll
        for (int j = 0; j < PP; ++j) {
            float d = fabsf(lon_own - lonj[j]);
            d = fminf(d, 360.0f - d);
            deg += (d < 10.0f) ? 1.0f : 0.0f;          // diag: d=0 -> 1
        }
        float dinv_own = rsqrtf(fmaxf(deg, 1e-12f));
        float dj[PP];
        #pragma unroll
        for (int j = 0; j < PP; ++j) dj[j] = __shfl(dinv_own, j, 32);

        if (l32 < PP) {
            _Float16* Ar = Am + (hh * 48 + wave * PP + l32) * AP2;
            half8v z = {0, 0, 0, 0, 0, 0, 0, 0};
            #pragma unroll
            for (int c = 0; c < 48; c += 8) *(half8v*)&Ar[c] = z;
            _Float16 vals[PP];
            #pragma unroll
            for (int j = 0; j < PP; ++j) {
                float d = fabsf(lon_own - lonj[j]);
                d = fminf(d, 360.0f - d);
                float a = (d < 10.0f) ? 1.0f : 0.0f;
                if (j == l32) a += 1.0f;               // A = mask + eye: diag = 2
                vals[j] = (_Float16)(a * dinv_own * dj[j]);
            }
            #pragma unroll
            for (int t4 = 0; t4 < 3; ++t4) {
                half4v v;
                v[0] = vals[4 * t4]; v[1] = vals[4 * t4 + 1];
                v[2] = vals[4 * t4 + 2]; v[3] = vals[4 * t4 + 3];
                *(half4v*)&Ar[wave * PP + 4 * t4] = v;
            }
        }
    }
    __syncthreads();   // A1: Am complete (all waves)

    // ---- hoist Ahat frags to VGPRs, BOTH halves (14 x half4v = 28 VGPR).
    // bAf[h] tiles (mt,nt): [0]=(0,0) [1]=(1,0) [2]=(0,1) [3]=(1,1) [4]=(2,1)
    // [5]=(1,2) [6]=(2,2); zero tiles (2,0),(0,2) skipped.
    // As B-frag: B[k=4q+j][col=qm] = Ahat[16nt+col][16mt+k]   (layers 0,1 mix)
    // As A-frag: A[row=qm][k=4q+j] = Ahat[16nt+row][16mt+k]   (layer 2 mix')
    half4v bAf[2][7];
    #pragma unroll
    for (int h = 0; h < 2; ++h) {
        const _Float16* Ah = Am + h * 48 * AP2;
        bAf[h][0] = *(const half4v*)&Ah[qm * AP2 + 4 * q];
        bAf[h][1] = *(const half4v*)&Ah[qm * AP2 + 16 + 4 * q];
        bAf[h][2] = *(const half4v*)&Ah[(16 + qm) * AP2 + 4 * q];
        bAf[h][3] = *(const half4v*)&Ah[(16 + qm) * AP2 + 16 + 4 * q];
        bAf[h][4] = *(const half4v*)&Ah[(16 + qm) * AP2 + 32 + 4 * q];
        bAf[h][5] = *(const half4v*)&Ah[(32 + qm) * AP2 + 16 + 4 * q];
        bAf[h][6] = *(const half4v*)&Ah[(32 + qm) * AP2 + 32 + 4 * q];
    }
    __syncthreads();   // A2: WAR — all bA reads done before proj overwrites hf

    // ---- pack half-A x, then issue half-B x loads (latency under proj-A) ----
    half8v bxA[3];
    #pragma unroll
    for (int nt = 0; nt < 3; ++nt) {
        half8v h;
        h[0] = (_Float16)xa[nt].x; h[1] = (_Float16)xa[nt].y;
        h[2] = (_Float16)xa[nt].z; h[3] = (_Float16)xa[nt].w;
        h[4] = (_Float16)xb[nt].x; h[5] = (_Float16)xb[nt].y;
        h[6] = (_Float16)xb[nt].z; h[7] = (_Float16)xb[nt].w;
        bxA[nt] = h;
    }
    #pragma unroll
    for (int nt = 0; nt < 3; ++nt) {
        const float* p = xblk + (48 + 16 * nt + qm) * DIN + 8 * q;
        xa[nt] = *(const float4*)p;
        xb[nt] = *(const float4*)(p + 4);
    }

    // ---- proj: both halves share the SAME aw/bias registers; C-init = bias ----
    {
        const int m0 = 32 * wave, m1 = 32 * wave + 16;
        half8v aw0 = *(const half8v*)&ws[(m0 + qm) * DIN + 8 * q];
        half8v aw1 = *(const half8v*)&ws[(m1 + qm) * DIN + 8 * q];
        float4 bi0 = *(const float4*)&b_in[m0 + 4 * q];
        float4 bi1 = *(const float4*)&b_in[m1 + 4 * q];
        const float4v ci0 = {bi0.x, bi0.y, bi0.z, bi0.w};   // C rows = ch 4q+r
        const float4v ci1 = {bi1.x, bi1.y, bi1.z, bi1.w};
        const int ho0 = (qm + 16 * ((q >> 1) & 3)) * 8 + (q & 1) * 4;        // mt2=0
        const int ho1 = (qm + 16 * ((2 + (q >> 1)) & 3)) * 8 + (q & 1) * 4;  // mt2=1
        #pragma unroll
        for (int nt = 0; nt < 3; ++nt) {
            float4v c0 = ci0, c1 = ci1;
            c0 = __builtin_amdgcn_mfma_f32_16x16x32_f16(aw0, bxA[nt], c0, 0, 0, 0);
            c1 = __builtin_amdgcn_mfma_f32_16x16x32_f16(aw1, bxA[nt], c1, 0, 0, 0);
            *(half4v*)&hf[0][nt * 4 + wave][ho0] = pk4(c0[0], c0[1], c0[2], c0[3]);
            *(half4v*)&hf[0][nt * 4 + wave][ho1] = pk4(c1[0], c1[1], c1[2], c1[3]);
        }
        half8v bxB[3];
        #pragma unroll
        for (int nt = 0; nt < 3; ++nt) {
            half8v h;
            h[0] = (_Float16)xa[nt].x; h[1] = (_Float16)xa[nt].y;
            h[2] = (_Float16)xa[nt].z; h[3] = (_Float16)xa[nt].w;
            h[4] = (_Float16)xb[nt].x; h[5] = (_Float16)xb[nt].y;
            h[6] = (_Float16)xb[nt].z; h[7] = (_Float16)xb[nt].w;
            bxB[nt] = h;
        }
        #pragma unroll
        for (int nt = 0; nt < 3; ++nt) {
            float4v c0 = ci0, c1 = ci1;
            c0 = __builtin_amdgcn_mfma_f32_16x16x32_f16(aw0, bxB[nt], c0, 0, 0, 0);
            c1 = __builtin_amdgcn_mfma_f32_16x16x32_f16(aw1, bxB[nt], c1, 0, 0, 0);
            *(half4v*)&hf[1][nt * 4 + wave][ho0] = pk4(c0[0], c0[1], c0[2], c0[3]);
            *(half4v*)&hf[1][nt * 4 + wave][ho1] = pk4(c1[0], c1[1], c1[2], c1[3]);
        }
    }

    // ---- layer-0 weight B-frags: issue BEFORE the barrier (latency hidden) ----
    half8v bw[2][4];
    #pragma unroll
    for (int n2 = 0; n2 < 2; ++n2)
        #pragma unroll
        for (int kt = 0; kt < 4; ++kt)
            bw[n2][kt] = *(const half8v*)&WgT[(32 * wave + 16 * n2 + qm) * H + 32 * kt + 8 * q];

    __syncthreads();   // B1: hf (both halves) complete

    #pragma unroll
    for (int l = 0; l < NL; ++l) {
        // t = h @ Wl for both halves, SHARED bw registers (all-static indexing)
        half4v ah[2][3][2];
        #pragma unroll
        for (int h = 0; h < 2; ++h) {
            float4v c[3][2];
            #pragma unroll
            for (int mt = 0; mt < 3; ++mt) {
                c[mt][0] = (float4v){0.f, 0.f, 0.f, 0.f};
                c[mt][1] = (float4v){0.f, 0.f, 0.f, 0.f};
            }
            #pragma unroll
            for (int kt = 0; kt < 4; ++kt)
                #pragma unroll
                for (int mt = 0; mt < 3; ++mt) {
                    half8v a = *(const half8v*)&hf[h][mt * 4 + kt][lane * 8];
                    c[mt][0] = __builtin_amdgcn_mfma_f32_16x16x32_f16(a, bw[0][kt], c[mt][0], 0, 0, 0);
                    c[mt][1] = __builtin_amdgcn_mfma_f32_16x16x32_f16(a, bw[1][kt], c[mt][1], 0, 0, 0);
                }
            #pragma unroll
            for (int mt = 0; mt < 3; ++mt)
                #pragma unroll
                for (int n2 = 0; n2 < 2; ++n2)
                    ah[h][mt][n2] = pk4(c[mt][n2][0], c[mt][n2][1], c[mt][n2][2], c[mt][n2][3]);
        }

        if (l < 2) {
            const float4 bg0 = *(const float4*)&b_gcn[l * H + 32 * wave + 4 * q];
            const float4 bg1 = *(const float4*)&b_gcn[l * H + 32 * wave + 16 + 4 * q];
            __syncthreads();   // WAR: all waves done reading hf (both halves)

            // prefetch next layer's W frags (bw dead; drains at RAW barrier)
            {
                const _Float16* Wn = WgT + (l + 1) * (H * H);
                #pragma unroll
                for (int n2 = 0; n2 < 2; ++n2)
                    #pragma unroll
                    for (int kt = 0; kt < 4; ++kt)
                        bw[n2][kt] = *(const half8v*)&Wn[(32 * wave + 16 * n2 + qm) * H + 32 * kt + 8 * q];
            }

            // mix per half: h'^T = t^T @ Ahat_h (bA persistent regs; D-init = bias)
            #pragma unroll
            for (int h = 0; h < 2; ++h) {
                #pragma unroll
                for (int n2 = 0; n2 < 2; ++n2) {
                    const float4 bg = n2 ? bg1 : bg0;
                    const float4v di = {bg.x, bg.y, bg.z, bg.w};   // D rows = ch 4q+r
                    const int hoff = (qm + 16 * ((2 * n2 + (q >> 1)) & 3)) * 8 + (q & 1) * 4;

                    float4v d0 = di;
                    d0 = __builtin_amdgcn_mfma_f32_16x16x16f16(ah[h][0][n2], bAf[h][0], d0, 0, 0, 0);
                    d0 = __builtin_amdgcn_mfma_f32_16x16x16f16(ah[h][1][n2], bAf[h][1], d0, 0, 0, 0);
                    *(half4v*)&hf[h][0 * 4 + wave][hoff] =
                        pk4(fmaxf(d0[0], 0.f), fmaxf(d0[1], 0.f),
                            fmaxf(d0[2], 0.f), fmaxf(d0[3], 0.f));

                    float4v d1 = di;
                    d1 = __builtin_amdgcn_mfma_f32_16x16x16f16(ah[h][0][n2], bAf[h][2], d1, 0, 0, 0);
                    d1 = __builtin_amdgcn_mfma_f32_16x16x16f16(ah[h][1][n2], bAf[h][3], d1, 0, 0, 0);
                    d1 = __builtin_amdgcn_mfma_f32_16x16x16f16(ah[h][2][n2], bAf[h][4], d1, 0, 0, 0);
                    *(half4v*)&hf[h][1 * 4 + wave][hoff] =
                        pk4(fmaxf(d1[0], 0.f), fmaxf(d1[1], 0.f),
                            fmaxf(d1[2], 0.f), fmaxf(d1[3], 0.f));

                    float4v d2 = di;
                    d2 = __builtin_amdgcn_mfma_f32_16x16x16f16(ah[h][1][n2], bAf[h][5], d2, 0, 0, 0);
                    d2 = __builtin_amdgcn_mfma_f32_16x16x16f16(ah[h][2][n2], bAf[h][6], d2, 0, 0, 0);
                    *(half4v*)&hf[h][2 * 4 + wave][hoff] =
                        pk4(fmaxf(d2[0], 0.f), fmaxf(d2[1], 0.f),
                            fmaxf(d2[2], 0.f), fmaxf(d2[3], 0.f));
                }
            }
            __syncthreads();   // RAW for next layer
        } else {
            // ---- layer 2: mix' = Ahat @ t per half (bA as A-frags, D-init = bias);
            // pool in-lane + shfl_xor; gTT aliases dead hf[0].
            __syncthreads();   // all hf reads done -> gTT/psf alias of hf is safe
            const float bgc0 = b_gcn[2 * H + 32 * wave + qm];
            const float bgc1 = b_gcn[2 * H + 32 * wave + 16 + qm];
            #pragma unroll
            for (int h = 0; h < 2; ++h) {
                float s[3][2];
                #pragma unroll
                for (int n2 = 0; n2 < 2; ++n2) {
                    const float bgc = n2 ? bgc1 : bgc0;
                    const float4v di = {bgc, bgc, bgc, bgc};   // D cols = ch qm (lane-uniform)
                    float4v d;
                    d = di;
                    d = __builtin_amdgcn_mfma_f32_16x16x16f16(bAf[h][0], ah[h][0][n2], d, 0, 0, 0);
                    d = __builtin_amdgcn_mfma_f32_16x16x16f16(bAf[h][1], ah[h][1][n2], d, 0, 0, 0);
                    s[0][n2] = fmaxf(d[0], 0.f) + fmaxf(d[1], 0.f)
                             + fmaxf(d[2], 0.f) + fmaxf(d[3], 0.f);
                    d = di;
                    d = __builtin_amdgcn_mfma_f32_16x16x16f16(bAf[h][2], ah[h][0][n2], d, 0, 0, 0);
                    d = __builtin_amdgcn_mfma_f32_16x16x16f16(bAf[h][3], ah[h][1][n2], d, 0, 0, 0);
                    d = __builtin_amdgcn_mfma_f32_16x16x16f16(bAf[h][4], ah[h][2][n2], d, 0, 0, 0);
                    s[1][n2] = fmaxf(d[0], 0.f) + fmaxf(d[1], 0.f)
                             + fmaxf(d[2], 0.f) + fmaxf(d[3], 0.f);
                    d = di;
                    d = __builtin_amdgcn_mfma_f32_16x16x16f16(bAf[h][5], ah[h][1][n2], d, 0, 0, 0);
                    d = __builtin_amdgcn_mfma_f32_16x16x16f16(bAf[h][6], ah[h][2][n2], d, 0, 0, 0);
                    s[2][n2] = fmaxf(d[0], 0.f) + fmaxf(d[1], 0.f)
                             + fmaxf(d[2], 0.f) + fmaxf(d[3], 0.f);
                }
                // batch(rt,q): b0:(0,q<=2) b1:(0,3)(1,0)(1,1) b2:(1,2)(1,3)(2,0) b3:(2,q>=1)
                #pragma unroll
                for (int n2 = 0; n2 < 2; ++n2) {
                    float g4[4];
                    g4[0] = (q <= 2) ? s[0][n2] : 0.f;
                    g4[1] = (q == 3) ? s[0][n2] : ((q <= 1) ? s[1][n2] : 0.f);
                    g4[2] = (q >= 2) ? s[1][n2] : ((q == 0) ? s[2][n2] : 0.f);
                    g4[3] = (q >= 1) ? s[2][n2] : 0.f;
                    #pragma unroll
                    for (int b = 0; b < 4; ++b) {
                        float v = g4[b];
                        v += __shfl_xor(v, 16, 64);
                        v += __shfl_xor(v, 32, 64);
                        if (q == 0)
                            gTT[(4 * h + b) * GTS + 32 * wave + 16 * n2 + qm] =
                                (_Float16)(v * (1.0f / 12.0f));
                    }
                }
            }
            __syncthreads();   // gTT complete
        }
    }

    // ---- out1 via MFMA: o1^T = W1T @ g^T; C-init = b_out1 ----
    const float4 b1v = *(const float4*)&b_out1[16 * wave + 4 * q];
    float4v acc = {b1v.x, b1v.y, b1v.z, b1v.w};
    #pragma unroll
    for (int kt = 0; kt < 4; ++kt) {
        half8v aW = *(const half8v*)&ws[WS_W1 + (16 * wave + qm) * H + 32 * kt + 8 * q];
        half8v bG = *(const half8v*)&gTT[qm * GTS + 32 * kt + 8 * q];
        acc = __builtin_amdgcn_mfma_f32_16x16x32_f16(aW, bG, acc, 0, 0, 0);
    }
    // lane holds o1T[o=16w+4q+r][b=qm] (valid qm<8; qm>=8 garbage, discarded)
    float o1v[4];
    o1v[0] = fmaxf(acc[0], 0.f);
    o1v[1] = fmaxf(acc[1], 0.f);
    o1v[2] = fmaxf(acc[2], 0.f);
    o1v[3] = fmaxf(acc[3], 0.f);
    const float* w2p = W_out2 + (16 * wave + 4 * q) * DOUT;   // 16B-aligned
    const float4 w2a = *(const float4*)(w2p);
    const float4 w2b = *(const float4*)(w2p + 4);
    const float4 w2c = *(const float4*)(w2p + 8);
    float p0 = o1v[0] * w2a.x + o1v[1] * w2a.w + o1v[2] * w2b.z + o1v[3] * w2c.y;
    float p1 = o1v[0] * w2a.y + o1v[1] * w2b.x + o1v[2] * w2b.w + o1v[3] * w2c.z;
    float p2 = o1v[0] * w2a.z + o1v[1] * w2b.y + o1v[2] * w2c.x + o1v[3] * w2c.w;
    p0 += __shfl_xor(p0, 16, 64); p0 += __shfl_xor(p0, 32, 64);
    p1 += __shfl_xor(p1, 16, 64); p1 += __shfl_xor(p1, 32, 64);
    p2 += __shfl_xor(p2, 16, 64); p2 += __shfl_xor(p2, 32, 64);
    if (q == 0 && qm < NB) {
        psf[wave * (NB * DOUT) + qm * DOUT + 0] = p0;
        psf[wave * (NB * DOUT) + qm * DOUT + 1] = p1;
        psf[wave * (NB * DOUT) + qm * DOUT + 2] = p2;
    }
    __syncthreads();
    if (tid < NB * DOUT) {   // 24
        const int b = tid / 3, d = tid - 3 * b;
        const float ssum = psf[b * 3 + d] + psf[24 + b * 3 + d]
                         + psf[48 + b * 3 + d] + psf[72 + b * 3 + d] + b_out2[d];
        out[(size_t)(b0 + b) * DOUT + d] = ssum;
    }
}

extern "C" void kernel_launch(void* const* d_in, const int* in_sizes, int n_in,
                              void* d_out, int out_size, void* d_ws, size_t ws_size,
                              hipStream_t stream) {
    const float* x      = (const float*)d_in[0];
    const float* W_in   = (const float*)d_in[1];
    const float* b_in   = (const float*)d_in[2];
    const float* W_gcn  = (const float*)d_in[3];
    const float* b_gcn  = (const float*)d_in[4];
    const float* W_out1 = (const float*)d_in[5];
    const float* b_out1 = (const float*)d_in[6];
    const float* W_out2 = (const float*)d_in[7];
    const float* b_out2 = (const float*)d_in[8];
    float* outp         = (float*)d_out;
    _Float16* wsh       = (_Float16*)d_ws;

    const int B = in_sizes[0] / (PP * DIN);        // 65536

    hipLaunchKernelGGL(prep_weights, dim3((WS_TOT + 255) / 256), dim3(256), 0, stream,
                       W_in, W_gcn, W_out1, wsh);
    hipLaunchKernelGGL(gnn_mfma, dim3(B / NB), dim3(256), 0, stream,
                       x, b_in, b_gcn, b_out1, W_out2, b_out2, wsh, outp);
}